// Round 8
// baseline (312.774 us; speedup 1.0000x reference)
//
#include <hip/hip_runtime.h>
#include <stdint.h>

typedef __attribute__((ext_vector_type(8))) __bf16 bf16x8;
typedef __attribute__((ext_vector_type(4))) float f32x4;

__device__ inline unsigned short f32_to_bf16_rne(float f) {
  union { float f; uint32_t u; } c; c.f = f;
  uint32_t u = c.u;
  uint32_t r = (u + 0x7FFFu + ((u >> 16) & 1u)) >> 16;
  return (unsigned short)r;
}

// ---------- pass 1: x (f32) -> A (bf16 bits) ----------
__global__ __launch_bounds__(256) void convert_x_kernel(const float* __restrict__ X,
                                                        unsigned short* __restrict__ A,
                                                        size_t n) {
  size_t i = (size_t)blockIdx.x * 256 + threadIdx.x;
  size_t stride = (size_t)gridDim.x * 256;
  for (size_t e = i * 4; e < n; e += stride * 4) {
    const float4 v = *reinterpret_cast<const float4*>(X + e);
    ushort4 o;
    o.x = f32_to_bf16_rne(v.x);
    o.y = f32_to_bf16_rne(v.y);
    o.z = f32_to_bf16_rne(v.z);
    o.w = f32_to_bf16_rne(v.w);
    *reinterpret_cast<ushort4*>(A + e) = o;
  }
}

// ---------- pass 2: Bt[n][k] = sign(Km[k][n]) as bf16 (+1/-1 exact) ----------
__global__ __launch_bounds__(256) void sign_transpose_kernel(const float* __restrict__ Km,
                                                             unsigned short* __restrict__ Bt,
                                                             int K, int N) {
  __shared__ unsigned short tile[64][65];
  const int k0 = blockIdx.x * 64;
  const int n0 = blockIdx.y * 64;
  const int t = threadIdx.x;
#pragma unroll
  for (int i = 0; i < 16; ++i) {
    int idx = t + i * 256;
    int kk = idx >> 6, nn = idx & 63;
    float v = Km[(size_t)(k0 + kk) * N + (n0 + nn)];
    tile[kk][nn] = (v >= 0.0f) ? (unsigned short)0x3F80u : (unsigned short)0xBF80u;
  }
  __syncthreads();
#pragma unroll
  for (int i = 0; i < 16; ++i) {
    int idx = t + i * 256;
    int nn = idx >> 6, kk = idx & 63;
    Bt[(size_t)(n0 + nn) * K + (k0 + kk)] = tile[kk][nn];
  }
}

// ---------- pass 3: 256x256-tile bf16 GEMM, 8-phase (m201-style) ----------
// A: [M][K] bf16 row-major; Bt: [N][K] bf16 row-major; C: [M][N] f32.
// 512 threads = 8 waves 2(M)x4(N); wave output 128x64; 16x16x32 MFMA.
// BK=64 K-tiles. LDS: 2 buffers, one K-tile each (A[256][64] + B[256][64] =
// 64 KiB, M-halves of 128 rows stored separately); kt g lives in buf g&1.
// 4 phases per K-tile, one C-quadrant each (q=(mh,nh); mh=A-row-half of the
// wave's 128 rows, nh=B-col-half of its 64 cols):
//   q0: ds_read A(mh0) 8 + B(nh0) 4 | stage | lgkm(8) | bar | lgkm0 | 16 MFMA | bar
//   q1: ds_read B(nh1) 4           | stage |          bar | lgkm0 | 16 MFMA | bar
//   q2: ds_read A(mh1) 8           | stage |          bar | lgkm0 | 16 MFMA | bar
//   q3: (no reads)                 | stage |          bar |         16 MFMA | vmcnt(2) | bar
// Staging stream: half-tiles numbered j (kt j>>2; j&3: 0=Ah0,1=Ah1,2=Bh0,
// 3=Bh1); global phase pi = 4*kt+q stages half j = pi+5 (clamped to last).
// LEDGER (all waves symmetric; barrier => block-wide):
//  RAW: before kt g opens (end of phase 4g-1), vmcnt(2) leaves only the
//    newest half-tile (2 loads) unconfirmed => halves <= 4g+3 landed, i.e.
//    all of kt g. Prologue stages halves 0..4 then vmcnt(2) => kt0 landed.
//  WAR: stage of half j (phase j-5) overwrites half j-8 (kt (j>>2)-2); all
//    reads of that kt drain at its q2 lgkm0, >= 1 closing barrier before
//    phase j-5. q3-phase stages (j&3==0) write the CURRENT buf's Ah0 region
//    of kt+2 -- safe: q3 issues no reads; kt's last reads drained at q2.
//  Tail: j clamps to last half (re-stages identical bytes; benign).
// SWIZZLE (8-slot involution, r5 lesson: XOR the whole slot): row = 128 B =
// 8 slots of 16 B; data of logical slot l (k = l*8) sits at phys l^(row&7).
// All frag-read row terms except llo are ==0 mod 8 => phys = (ks*4+lhi) ^
// (llo&7); ks toggles slot bit2 => addr(ks=1) = addr(ks=0) ^ 32 shorts (all
// other addr terms have bit5 clear). Bank check per 16-lane group: rows
// 0..15, phys slot = const ^ (llo&7) -> 8 slot values x 2 lanes each ->
// every bank exactly 2 lanes = free (m136).

__device__ __forceinline__ void stage_half(const unsigned short* __restrict__ G,
                                           size_t grow0, int K, int k0,
                                           unsigned short* lds_half_base,  // block-uniform
                                           int tid, int wv) {
#pragma unroll
  for (int i = 0; i < 2; ++i) {
    const int row = i * 64 + (tid >> 3);              // 0..127 within half
    const int slot = (tid & 7) ^ (row & 7);           // pre-swizzled source slot
    const unsigned short* ga = G + (grow0 + row) * (size_t)K + k0 + slot * 8;
    __builtin_amdgcn_global_load_lds(
        (const __attribute__((address_space(1))) void*)ga,
        (__attribute__((address_space(3))) void*)(lds_half_base + i * 4096 + wv * 512),
        16, 0, 0);
  }
}

// One phase. T = iter (2 K-tiles), KT = 0/1 (buf parity == KT), Q = quadrant.
#define PHASE(T, KT, Q)                                                                 \
  {                                                                                     \
    constexpr int mh = ((Q) >> 1) & 1, nh = (Q) & 1;                                    \
    constexpr int dcur = (KT) * 32768;                                                  \
    if constexpr ((Q) == 0) {                                                           \
      _Pragma("unroll") for (int fr = 0; fr < 4; ++fr)                                  \
        _Pragma("unroll") for (int ks = 0; ks < 2; ++ks)                                \
          a[fr][ks] = *reinterpret_cast<const bf16x8*>(                                 \
              &lds[(dcur + aoff + fr * 1024) ^ (ks << 5)]);                             \
      _Pragma("unroll") for (int fc = 0; fc < 2; ++fc)                                  \
        _Pragma("unroll") for (int ks = 0; ks < 2; ++ks)                                \
          b[0][fc][ks] = *reinterpret_cast<const bf16x8*>(                              \
              &lds[(dcur + boff + fc * 1024) ^ (ks << 5)]);                             \
    } else if constexpr ((Q) == 1) {                                                    \
      _Pragma("unroll") for (int fc = 0; fc < 2; ++fc)                                  \
        _Pragma("unroll") for (int ks = 0; ks < 2; ++ks)                                \
          b[1][fc][ks] = *reinterpret_cast<const bf16x8*>(                              \
              &lds[(dcur + boff + 2048 + fc * 1024) ^ (ks << 5)]);                      \
    } else if constexpr ((Q) == 2) {                                                    \
      _Pragma("unroll") for (int fr = 0; fr < 4; ++fr)                                  \
        _Pragma("unroll") for (int ks = 0; ks < 2; ++ks)                                \
          a[fr][ks] = *reinterpret_cast<const bf16x8*>(                                 \
              &lds[(dcur + aoff + 4096 + fr * 1024) ^ (ks << 5)]);                      \
    }                                                                                   \
    {                                                                                   \
      int j = 8 * (T) + 4 * (KT) + (Q) + 5;                                             \
      if (j > JMAX) j = JMAX;                                                           \
      const int kj = j >> 2, rr = j & 3, hh = rr & 1;                                   \
      const unsigned short* SG = (rr < 2) ? A : Bt;                                     \
      const size_t g0 = ((rr < 2) ? a_row0 : b_row0) + (size_t)hh * 128;                \
      unsigned short* lb = (unsigned short*)lds + (kj & 1) * 32768 +                    \
                           ((rr < 2) ? 0 : 16384) + hh * 8192;                          \
      stage_half(SG, g0, K, kj * 64, lb, tid, wv);                                      \
    }                                                                                   \
    if constexpr ((Q) == 0) asm volatile("s_waitcnt lgkmcnt(8)\n" ::: "memory");        \
    __builtin_amdgcn_s_barrier();                                                       \
    asm volatile("s_waitcnt lgkmcnt(0)\n" ::: "memory");                                \
    __builtin_amdgcn_sched_barrier(0);                                                  \
    __builtin_amdgcn_s_setprio(1);                                                      \
    _Pragma("unroll") for (int ks = 0; ks < 2; ++ks)                                    \
      _Pragma("unroll") for (int fr = 0; fr < 4; ++fr)                                  \
        _Pragma("unroll") for (int fc = 0; fc < 2; ++fc)                                \
          acc[mh * 4 + fr][nh * 2 + fc] = __builtin_amdgcn_mfma_f32_16x16x32_bf16(      \
              a[fr][ks], b[nh][fc][ks], acc[mh * 4 + fr][nh * 2 + fc], 0, 0, 0);        \
    __builtin_amdgcn_s_setprio(0);                                                      \
    if constexpr ((Q) == 3) asm volatile("s_waitcnt vmcnt(2)\n" ::: "memory");          \
    __builtin_amdgcn_s_barrier();                                                       \
  }

__global__ __launch_bounds__(512, 2) void gemm_bf16_256(const unsigned short* __restrict__ A,
                                                        const unsigned short* __restrict__ Bt,
                                                        float* __restrict__ C,
                                                        int M, int N, int K) {
  __shared__ unsigned short lds[2 * 32768];  // 128 KiB; buf d: A halves @0,8192; B @16384,24576

  const int nBN = N >> 8;
  const int nwg = gridDim.x;
  const int bid = blockIdx.x;
  int swz = bid;
  if ((nwg & 7) == 0) {  // bijective XCD swizzle
    const int q = nwg >> 3;
    swz = (bid & 7) * q + (bid >> 3);
  }
  const size_t a_row0 = (size_t)(swz / nBN) * 256;
  const size_t b_row0 = (size_t)(swz % nBN) * 256;

  const int tid = threadIdx.x;
  const int wv = tid >> 6, ln = tid & 63;
  const int llo = ln & 15, lhi = ln >> 4;
  const int wr = wv >> 2, wc = wv & 3;

  // ds_read bases (shorts). phys slot(ks=0) = lhi ^ (llo&7); ks=1 -> ^32.
  const int slot0 = (lhi ^ (llo & 7)) * 8;
  const int aoff = wr * 8192 + llo * 64 + slot0;                          // +mh*4096+fr*1024
  const int boff = 16384 + (wc >> 1) * 8192 + (wc & 1) * 4096 + llo * 64 + slot0;  // +nh*2048+fc*1024

  const int NI = K >> 7;        // iters of 2 K-tiles (K%128==0)
  const int JMAX = (K >> 4) - 1;  // last half-tile index = 4*(K/64)-1

  f32x4 acc[8][4];
#pragma unroll
  for (int i = 0; i < 8; ++i)
#pragma unroll
    for (int j = 0; j < 4; ++j) acc[i][j] = (f32x4){0.f, 0.f, 0.f, 0.f};

  bf16x8 a[4][2], b[2][2][2];

  // ---- prologue: stage halves 0..4 (kt0 all + kt1 Ah0); confirm kt0 ----
  stage_half(A, a_row0, K, 0, (unsigned short*)lds, tid, wv);
  stage_half(A, a_row0 + 128, K, 0, (unsigned short*)lds + 8192, tid, wv);
  stage_half(Bt, b_row0, K, 0, (unsigned short*)lds + 16384, tid, wv);
  stage_half(Bt, b_row0 + 128, K, 0, (unsigned short*)lds + 24576, tid, wv);
  stage_half(A, a_row0, K, 64, (unsigned short*)lds + 32768, tid, wv);
  asm volatile("s_waitcnt vmcnt(2)\n" ::: "memory");
  __builtin_amdgcn_s_barrier();

  // ---- main loop: 8 phases per iter (2 K-tiles) ----
  for (int t = 0; t < NI; ++t) {
    PHASE(t, 0, 0) PHASE(t, 0, 1) PHASE(t, 0, 2) PHASE(t, 0, 3)
    PHASE(t, 1, 0) PHASE(t, 1, 1) PHASE(t, 1, 2) PHASE(t, 1, 3)
  }

  // ---- epilogue: C/D layout col = lane&15, row = (lane>>4)*4 + reg ----
#pragma unroll
  for (int mi = 0; mi < 8; ++mi) {
#pragma unroll
    for (int ni = 0; ni < 4; ++ni) {
      const size_t col = b_row0 + wc * 64 + ni * 16 + llo;
      const size_t rbase = a_row0 + wr * 128 + mi * 16 + lhi * 4;
#pragma unroll
      for (int j = 0; j < 4; ++j)
        C[(rbase + j) * (size_t)N + col] = acc[mi][ni][j];
    }
  }
}

// ---------- fallback: f32 tiled GEMM (only if ws_size too small) ----------
__global__ __launch_bounds__(256) void gemm_f32_fallback(const float* __restrict__ X,
                                                         const float* __restrict__ Km,
                                                         float* __restrict__ C,
                                                         int M, int N, int K) {
  __shared__ float As[64][16];
  __shared__ float Bs[16][65];
  const int nBN = N / 64;
  const int bm = blockIdx.x / nBN;
  const int bn = blockIdx.x % nBN;
  const int t = threadIdx.x;
  const int tx = t & 15, ty = t >> 4;
  float acc[4][4] = {};
  for (int kb = 0; kb < K; kb += 16) {
#pragma unroll
    for (int i = 0; i < 4; ++i) {
      int e = t + i * 256;
      int r = e >> 4, c = e & 15;
      As[r][c] = X[(size_t)(bm * 64 + r) * K + kb + c];
      int rk = e >> 6, cn = e & 63;
      float v = Km[(size_t)(kb + rk) * N + bn * 64 + cn];
      Bs[rk][cn] = (v >= 0.f) ? 1.f : -1.f;
    }
    __syncthreads();
#pragma unroll
    for (int kk = 0; kk < 16; ++kk) {
      float a[4], b[4];
#pragma unroll
      for (int r = 0; r < 4; ++r) a[r] = As[ty * 4 + r][kk];
#pragma unroll
      for (int c = 0; c < 4; ++c) b[c] = Bs[kk][tx * 4 + c];
#pragma unroll
      for (int r = 0; r < 4; ++r)
#pragma unroll
        for (int c = 0; c < 4; ++c) acc[r][c] += a[r] * b[c];
    }
    __syncthreads();
  }
#pragma unroll
  for (int r = 0; r < 4; ++r)
#pragma unroll
    for (int c = 0; c < 4; ++c)
      C[(size_t)(bm * 64 + ty * 4 + r) * N + bn * 64 + tx * 4 + c] = acc[r][c];
}

extern "C" void kernel_launch(void* const* d_in, const int* in_sizes, int n_in,
                              void* d_out, int out_size, void* d_ws, size_t ws_size,
                              hipStream_t stream) {
  const float* x = (const float*)d_in[0];
  const float* kern = (const float*)d_in[1];
  float* out = (float*)d_out;

  const int K = 4096;             // D_IN
  const int N = 4096;             // UNITS
  const int M = in_sizes[0] / K;  // 8192

  const size_t a_bytes = (size_t)M * K * 2;
  const size_t b_bytes = (size_t)N * K * 2;

  if (ws_size >= a_bytes + b_bytes && (M % 256) == 0 && (N % 256) == 0 && (K % 128) == 0) {
    unsigned short* A = (unsigned short*)d_ws;
    unsigned short* Bt = (unsigned short*)((char*)d_ws + a_bytes);
    convert_x_kernel<<<2048, 256, 0, stream>>>(x, A, (size_t)M * K);
    sign_transpose_kernel<<<dim3(K / 64, N / 64), 256, 0, stream>>>(kern, Bt, K, N);
    gemm_bf16_256<<<(M / 256) * (N / 256), 512, 0, stream>>>(A, Bt, out, M, N, K);
  } else {
    gemm_f32_fallback<<<(M / 64) * (N / 64), 256, 0, stream>>>(x, kern, out, M, N, K);
  }
}

// Round 10
// 272.183 us; speedup vs baseline: 1.1491x; 1.1491x over previous
//
#include <hip/hip_runtime.h>
#include <stdint.h>

typedef __attribute__((ext_vector_type(8))) __bf16 bf16x8;
typedef __attribute__((ext_vector_type(4))) float f32x4;

__device__ inline unsigned short f32_to_bf16_rne(float f) {
  union { float f; uint32_t u; } c; c.f = f;
  uint32_t u = c.u;
  uint32_t r = (u + 0x7FFFu + ((u >> 16) & 1u)) >> 16;
  return (unsigned short)r;
}

// ---------- pass 1: x (f32) -> A (bf16 bits) ----------
__global__ __launch_bounds__(256) void convert_x_kernel(const float* __restrict__ X,
                                                        unsigned short* __restrict__ A,
                                                        size_t n) {
  size_t i = (size_t)blockIdx.x * 256 + threadIdx.x;
  size_t stride = (size_t)gridDim.x * 256;
  for (size_t e = i * 4; e < n; e += stride * 4) {
    const float4 v = *reinterpret_cast<const float4*>(X + e);
    ushort4 o;
    o.x = f32_to_bf16_rne(v.x);
    o.y = f32_to_bf16_rne(v.y);
    o.z = f32_to_bf16_rne(v.z);
    o.w = f32_to_bf16_rne(v.w);
    *reinterpret_cast<ushort4*>(A + e) = o;
  }
}

// ---------- pass 2: Bt[n][k] = sign(Km[k][n]) as bf16 (+1/-1 exact) ----------
__global__ __launch_bounds__(256) void sign_transpose_kernel(const float* __restrict__ Km,
                                                             unsigned short* __restrict__ Bt,
                                                             int K, int N) {
  __shared__ unsigned short tile[64][65];
  const int k0 = blockIdx.x * 64;
  const int n0 = blockIdx.y * 64;
  const int t = threadIdx.x;
#pragma unroll
  for (int i = 0; i < 16; ++i) {
    int idx = t + i * 256;
    int kk = idx >> 6, nn = idx & 63;
    float v = Km[(size_t)(k0 + kk) * N + (n0 + nn)];
    tile[kk][nn] = (v >= 0.0f) ? (unsigned short)0x3F80u : (unsigned short)0xBF80u;
  }
  __syncthreads();
#pragma unroll
  for (int i = 0; i < 16; ++i) {
    int idx = t + i * 256;
    int nn = idx >> 6, kk = idx & 63;
    Bt[(size_t)(n0 + nn) * K + (k0 + kk)] = tile[kk][nn];
  }
}

// ---------- pass 3: 256x256-tile bf16 MFMA GEMM, reg-double-buffered ----------
// r4/r7 skeleton (16x16x32, 4-deep BK=32 ring, 0 bank conflicts, ledger
// proven over r2-r7) with ONE scheduling change and NO sync change:
// the two 16-MFMA clusters are split into four 8-MFMA sub-clusters with the
// 12 ds_reads distributed 4/2/4/2 between them (m196: fine interleave is the
// lever; r8 showed per-phase barriers are not). Reads/stages/waits are
// bit-identical to r7 -- correctness ledger carries over unchanged:
//  - one s_waitcnt vmcnt(4) + one s_barrier per iter
//  - entering iter t: tiles <= t+1 landed from all waves (vmcnt(4) at end of
//    t-1 allows only tile t+3's 4 loads outstanding, issued >= 1 full iter
//    earlier => no drain stall)
//  - staging target buf[(t+3)&3]=buf[(t-1)&3] fully consumed before B(t-1)
//  - tail: ts clamps to NT-1 (re-stage identical bytes); nb clamps to cb
// T2 swizzle: row = 64 B = 4 slots of 16 B; slot ^= (row>>1)&3 (2-way free).
// gl_lds dest linear; GLOBAL source k-chunk pre-swizzled (rule 21).
// 8-phase/BK=64 variants REJECTED by measurement (r8: 41% MfmaUtil) and by
// resource analysis (ring-3 BK=64 = 192 KiB > 160; 2 blocks/CU impossible:
// acc alone = 128 regs).
// (r9 fix: MFMA8 now takes BFRAG explicitly -- macro hygiene, no semantic change.)

__device__ __forceinline__ void stage_mat(const unsigned short* __restrict__ G,
                                          size_t grow0, int K, int k0,
                                          unsigned short* lds_wave_base,  // wave-uniform
                                          int tid) {
#pragma unroll
  for (int i = 0; i < 2; ++i) {
    const int row = i * 128 + (tid >> 2);                 // 0..255
    const int srcslot = (tid & 3) ^ ((row >> 1) & 3);     // pre-swizzled source
    const unsigned short* ga = G + (grow0 + row) * (size_t)K + k0 + srcslot * 8;
    __builtin_amdgcn_global_load_lds(
        (const __attribute__((address_space(1))) void*)ga,
        (__attribute__((address_space(3))) void*)(lds_wave_base + i * 4096),
        16, 0, 0);
  }
}

#define MFMA8(ACCR, AFRAG, BFRAG, I0, I1)                                             \
  __builtin_amdgcn_s_setprio(1);                                                     \
  _Pragma("unroll")                                                                   \
  for (int mi = (I0); mi < (I1); ++mi)                                                \
    _Pragma("unroll")                                                                 \
    for (int ni = 0; ni < 4; ++ni)                                                    \
      acc[(ACCR) + mi][ni] = __builtin_amdgcn_mfma_f32_16x16x32_bf16(                 \
          AFRAG[mi], BFRAG[ni], acc[(ACCR) + mi][ni], 0, 0, 0);                       \
  __builtin_amdgcn_s_setprio(0);                                                      \
  __builtin_amdgcn_sched_barrier(0);

// One pipelined iteration. AFC/BFC: current cluster-0 operands (already in
// regs). AFN/BFN: written with next iteration's cluster-0 operands.
#define GEMM_ITER(T, AFC, BFC, AFN, BFN)                                              \
  {                                                                                   \
    const int cb = ((T) & 3) * 16384;                                                 \
    const int ts = ((T) + 3 < NTt) ? ((T) + 3) : (NTt - 1);                           \
    const int tb = (ts & 3) * 16384;                                                  \
    const int nb = ((T) + 1 < NTt) ? ((((T) + 1) & 3) * 16384) : cb;                  \
    bf16x8 af1[4];                                                                    \
    /* group 1: af1 reads (4) + A-stage */                                            \
    _Pragma("unroll")                                                                 \
    for (int mi = 0; mi < 4; ++mi)                                                    \
      af1[mi] = *reinterpret_cast<const bf16x8*>(&lds[cb + aoff + 2048 + mi * 512]);  \
    stage_mat(A, a_row0, K, ts * 32, &lds[tb + wv * 512], tid);                       \
    __builtin_amdgcn_sched_barrier(0);                                                \
    MFMA8(0, AFC, BFC, 0, 2)                                                          \
    /* group 2: next-B reads (2) */                                                   \
    _Pragma("unroll")                                                                 \
    for (int ni = 0; ni < 2; ++ni)                                                    \
      BFN[ni] = *reinterpret_cast<const bf16x8*>(&lds[nb + boff + ni * 512]);         \
    __builtin_amdgcn_sched_barrier(0);                                                \
    MFMA8(0, AFC, BFC, 2, 4)                                                          \
    /* group 3: next-B (2) + next-A (2) reads + B-stage */                            \
    _Pragma("unroll")                                                                 \
    for (int ni = 2; ni < 4; ++ni)                                                    \
      BFN[ni] = *reinterpret_cast<const bf16x8*>(&lds[nb + boff + ni * 512]);         \
    _Pragma("unroll")                                                                 \
    for (int mi = 0; mi < 2; ++mi)                                                    \
      AFN[mi] = *reinterpret_cast<const bf16x8*>(&lds[nb + aoff + mi * 512]);         \
    stage_mat(Bt, b_row0, K, ts * 32, &lds[tb + 8192 + wv * 512], tid);               \
    __builtin_amdgcn_sched_barrier(0);                                                \
    MFMA8(4, af1, BFC, 0, 2)                                                          \
    /* group 4: next-A reads (2) */                                                   \
    _Pragma("unroll")                                                                 \
    for (int mi = 2; mi < 4; ++mi)                                                    \
      AFN[mi] = *reinterpret_cast<const bf16x8*>(&lds[nb + aoff + mi * 512]);         \
    __builtin_amdgcn_sched_barrier(0);                                                \
    MFMA8(4, af1, BFC, 2, 4)                                                          \
    asm volatile("s_waitcnt vmcnt(4)\n" ::: "memory");                                \
    __builtin_amdgcn_s_barrier();                                                     \
  }

__global__ __launch_bounds__(512, 2) void gemm_bf16_256(const unsigned short* __restrict__ A,
                                                        const unsigned short* __restrict__ Bt,
                                                        float* __restrict__ C,
                                                        int M, int N, int K) {
  __shared__ unsigned short lds[4 * 16384];  // 128 KiB; per buf: A[256][32] then B[256][32]

  const int nBN = N >> 8;
  const int nwg = gridDim.x;
  const int bid = blockIdx.x;
  int swz = bid;
  if ((nwg & 7) == 0) {  // bijective XCD swizzle
    const int q = nwg >> 3;
    swz = (bid & 7) * q + (bid >> 3);
  }
  const size_t a_row0 = (size_t)(swz / nBN) * 256;
  const size_t b_row0 = (size_t)(swz % nBN) * 256;

  const int tid = threadIdx.x;
  const int wv = tid >> 6, ln = tid & 63;
  const int llo = ln & 15, lhi = ln >> 4;
  const int wr = wv >> 2, wc = wv & 3;
  const int sA = lhi ^ ((llo >> 1) & 3);  // swizzled 16B-slot for ds_read

  // per-lane ds_read bases (shorts, relative to buf start)
  const int aoff = (wr * 128 + llo) * 32 + sA * 8;
  const int boff = 8192 + (wc * 64 + llo) * 32 + sA * 8;

  const int NTt = K >> 5;  // 128 K-tiles (even; launch guards K%128==0)

  f32x4 acc[8][4];
#pragma unroll
  for (int i = 0; i < 8; ++i)
#pragma unroll
    for (int j = 0; j < 4; ++j) acc[i][j] = (f32x4){0.f, 0.f, 0.f, 0.f};

  // ---- prologue: stage tiles 0,1,2; confirm tiles 0 AND 1; preload t=0 ----
#pragma unroll
  for (int tt = 0; tt < 3; ++tt) {
    stage_mat(A, a_row0, K, tt * 32, &lds[tt * 16384 + wv * 512], tid);
    stage_mat(Bt, b_row0, K, tt * 32, &lds[tt * 16384 + 8192 + wv * 512], tid);
  }
  asm volatile("s_waitcnt vmcnt(4)\n" ::: "memory");
  __builtin_amdgcn_s_barrier();

  bf16x8 af0_a[4], bfr_a[4], af0_b[4], bfr_b[4];
#pragma unroll
  for (int ni = 0; ni < 4; ++ni)
    bfr_a[ni] = *reinterpret_cast<const bf16x8*>(&lds[boff + ni * 512]);
#pragma unroll
  for (int mi = 0; mi < 4; ++mi)
    af0_a[mi] = *reinterpret_cast<const bf16x8*>(&lds[aoff + mi * 512]);

  // ---- main loop: 2x unrolled, ping-pong register sets ----
  for (int t = 0; t < NTt; t += 2) {
    GEMM_ITER(t, af0_a, bfr_a, af0_b, bfr_b)
    GEMM_ITER(t + 1, af0_b, bfr_b, af0_a, bfr_a)
  }

  // ---- epilogue: C/D layout col = lane&15, row = (lane>>4)*4 + reg ----
#pragma unroll
  for (int mi = 0; mi < 8; ++mi) {
#pragma unroll
    for (int ni = 0; ni < 4; ++ni) {
      const size_t col = b_row0 + wc * 64 + ni * 16 + llo;
      const size_t rbase = a_row0 + wr * 128 + mi * 16 + lhi * 4;
#pragma unroll
      for (int j = 0; j < 4; ++j)
        C[(rbase + j) * (size_t)N + col] = acc[mi][ni][j];
    }
  }
}

// ---------- fallback: f32 tiled GEMM (only if ws_size too small) ----------
__global__ __launch_bounds__(256) void gemm_f32_fallback(const float* __restrict__ X,
                                                         const float* __restrict__ Km,
                                                         float* __restrict__ C,
                                                         int M, int N, int K) {
  __shared__ float As[64][16];
  __shared__ float Bs[16][65];
  const int nBN = N / 64;
  const int bm = blockIdx.x / nBN;
  const int bn = blockIdx.x % nBN;
  const int t = threadIdx.x;
  const int tx = t & 15, ty = t >> 4;
  float acc[4][4] = {};
  for (int kb = 0; kb < K; kb += 16) {
#pragma unroll
    for (int i = 0; i < 4; ++i) {
      int e = t + i * 256;
      int r = e >> 4, c = e & 15;
      As[r][c] = X[(size_t)(bm * 64 + r) * K + kb + c];
      int rk = e >> 6, cn = e & 63;
      float v = Km[(size_t)(kb + rk) * N + bn * 64 + cn];
      Bs[rk][cn] = (v >= 0.f) ? 1.f : -1.f;
    }
    __syncthreads();
#pragma unroll
    for (int kk = 0; kk < 16; ++kk) {
      float a[4], b[4];
#pragma unroll
      for (int r = 0; r < 4; ++r) a[r] = As[ty * 4 + r][kk];
#pragma unroll
      for (int c = 0; c < 4; ++c) b[c] = Bs[kk][tx * 4 + c];
#pragma unroll
      for (int r = 0; r < 4; ++r)
#pragma unroll
        for (int c = 0; c < 4; ++c) acc[r][c] += a[r] * b[c];
    }
    __syncthreads();
  }
#pragma unroll
  for (int r = 0; r < 4; ++r)
#pragma unroll
    for (int c = 0; c < 4; ++c)
      C[(size_t)(bm * 64 + ty * 4 + r) * N + bn * 64 + tx * 4 + c] = acc[r][c];
}

extern "C" void kernel_launch(void* const* d_in, const int* in_sizes, int n_in,
                              void* d_out, int out_size, void* d_ws, size_t ws_size,
                              hipStream_t stream) {
  const float* x = (const float*)d_in[0];
  const float* kern = (const float*)d_in[1];
  float* out = (float*)d_out;

  const int K = 4096;             // D_IN
  const int N = 4096;             // UNITS
  const int M = in_sizes[0] / K;  // 8192

  const size_t a_bytes = (size_t)M * K * 2;
  const size_t b_bytes = (size_t)N * K * 2;

  if (ws_size >= a_bytes + b_bytes && (M % 256) == 0 && (N % 256) == 0 && (K % 128) == 0) {
    unsigned short* A = (unsigned short*)d_ws;
    unsigned short* Bt = (unsigned short*)((char*)d_ws + a_bytes);
    convert_x_kernel<<<2048, 256, 0, stream>>>(x, A, (size_t)M * K);
    sign_transpose_kernel<<<dim3(K / 64, N / 64), 256, 0, stream>>>(kern, Bt, K, N);
    gemm_bf16_256<<<(M / 256) * (N / 256), 512, 0, stream>>>(A, Bt, out, M, N, K);
  } else {
    gemm_f32_fallback<<<(M / 64) * (N / 64), 256, 0, stream>>>(x, kern, out, M, N, K);
  }
}